// Round 3
// baseline (299.594 us; speedup 1.0000x reference)
//
#include <hip/hip_runtime.h>
#include <stdint.h>

#define NUM_C 16
#define NUM_B 8
#define NBKT (NUM_C * 64)                // 1024 buckets per batch
#define NGRP 256                         // mode groups (4 buckets each)
#define CHUNK_S 8192                     // items per sort chunk
#define TAB 4096                         // LDS hash slots per mode block
#define MODE_CAP 3072                    // staging cap PER sub-bucket (25 sigma)
#define MAX_NB 8

__device__ __forceinline__ unsigned hash_u32(unsigned h) {
    h ^= h >> 16; h *= 0x85ebca6bu;
    h ^= h >> 13; h *= 0xc2b2ae35u;
    h ^= h >> 16;
    return h;                            // invertible (xorshift-mul) mixer
}
__device__ __forceinline__ unsigned canon_key(float v) {
    unsigned k = __float_as_uint(v);
    return (k == 0x80000000u) ? 0u : k;  // -0.0 == +0.0
}
__device__ __forceinline__ unsigned bucket_of(unsigned key, int c) {
    return ((unsigned)c << 6) | (hash_u32(key) >> 26);
}

// K1 (fused hist + chunk-local counting sort): one pass over x,t.
// Per 8192-item chunk: LDS histogram (1 returning atomic/item), wave-shfl
// scan of the 1024 buckets (3 barriers, was 20), bucket-sorted placement in
// LDS, coalesced uint4 write-out. Offsets written TRANSPOSED:
// offsT[lb][row 0..1024][chunk] (u16) so mode reads coalesced rows.
__global__ void __launch_bounds__(512)
sort_kernel(const float* __restrict__ x, const int* __restrict__ t,
            long long N, int bbase, int nchunk, int nchpad,
            unsigned* __restrict__ keysout, unsigned short* __restrict__ offsT)
{
    __shared__ unsigned hist[NBKT];      // counts -> inclusive scan
    __shared__ unsigned lout[CHUNK_S];   // 32 KiB
    __shared__ unsigned wsum[8];
    const int lb = blockIdx.x / nchunk;
    const int ch = blockIdx.x % nchunk;
    const int b  = bbase + lb;
    const long long base = (long long)ch * CHUNK_S;
    const int count = (int)((N - base < CHUNK_S) ? (N - base) : CHUNK_S);
    const float* xb = x + (size_t)b * N + base;
    const int*   tb = t + (size_t)b * N + base;
    const int tid = threadIdx.x;

    for (int i = tid; i < NBKT; i += 512) hist[i] = 0u;
    __syncthreads();

    unsigned keys[16], pk[16];           // pk = bucket<<13 | rank
    const int n4 = count >> 2;
    #pragma unroll
    for (int r = 0; r < 4; ++r) {
        const int idx4 = tid + r * 512;
        if (idx4 < n4) {
            float4 v  = ((const float4*)xb)[idx4];
            int4   cc = ((const int4*)tb)[idx4];
            unsigned k0 = canon_key(v.x), b0 = bucket_of(k0, cc.x);
            unsigned k1 = canon_key(v.y), b1 = bucket_of(k1, cc.y);
            unsigned k2 = canon_key(v.z), b2 = bucket_of(k2, cc.z);
            unsigned k3 = canon_key(v.w), b3 = bucket_of(k3, cc.w);
            unsigned p0 = atomicAdd(&hist[b0], 1u);
            unsigned p1 = atomicAdd(&hist[b1], 1u);
            unsigned p2 = atomicAdd(&hist[b2], 1u);
            unsigned p3 = atomicAdd(&hist[b3], 1u);
            keys[r*4+0] = k0; pk[r*4+0] = (b0 << 13) | p0;
            keys[r*4+1] = k1; pk[r*4+1] = (b1 << 13) | p1;
            keys[r*4+2] = k2; pk[r*4+2] = (b2 << 13) | p2;
            keys[r*4+3] = k3; pk[r*4+3] = (b3 << 13) | p3;
        }
    }
    unsigned kex = 0u, pkx = 0u; int hex = 0;
    {
        const int remi = (n4 << 2) + tid;  // <=3 tail items
        if (remi < count) {
            unsigned k = canon_key(xb[remi]);
            unsigned bk = bucket_of(k, tb[remi]);
            unsigned p = atomicAdd(&hist[bk], 1u);
            kex = k; pkx = (bk << 13) | p; hex = 1;
        }
    }
    __syncthreads();

    // inclusive scan of hist[0..1023]: 2 bins/thread, wave shfl scan
    {
        unsigned b0v = hist[2 * tid], b1v = hist[2 * tid + 1];
        unsigned s = b0v + b1v, inc = s;
        const int lane = tid & 63;
        #pragma unroll
        for (int d = 1; d < 64; d <<= 1) {
            unsigned tt = __shfl_up(inc, d);
            if (lane >= d) inc += tt;
        }
        if (lane == 63) wsum[tid >> 6] = inc;
        __syncthreads();
        unsigned wbase = 0;
        for (int i = 0; i < (tid >> 6); ++i) wbase += wsum[i];
        unsigned excl = wbase + inc - s;
        hist[2 * tid]     = excl + b0v;
        hist[2 * tid + 1] = excl + s;
        __syncthreads();
    }

    #pragma unroll
    for (int r = 0; r < 4; ++r) {
        const int idx4 = tid + r * 512;
        if (idx4 < n4) {
            #pragma unroll
            for (int c2 = 0; c2 < 4; ++c2) {
                unsigned bk = pk[r*4+c2] >> 13, p = pk[r*4+c2] & 8191u;
                lout[(bk ? hist[bk - 1] : 0u) + p] = keys[r*4+c2];
            }
        }
    }
    if (hex) {
        unsigned bk = pkx >> 13, p = pkx & 8191u;
        lout[(bk ? hist[bk - 1] : 0u) + p] = kex;
    }
    __syncthreads();

    unsigned* kb = keysout + (size_t)lb * N + base;
    if (count == CHUNK_S) {
        #pragma unroll
        for (int r = 0; r < 4; ++r)
            ((uint4*)kb)[tid + r * 512] = ((const uint4*)lout)[tid + r * 512];
    } else {
        for (int i = tid; i < count; i += 512) kb[i] = lout[i];
    }
    // transposed offsets: column ch of each row (bucket start), u16
    unsigned short* ocol = offsT + (size_t)lb * 1025 * nchpad + ch;
    ocol[(size_t)tid * nchpad] = (unsigned short)(tid ? hist[tid - 1] : 0u);
    ocol[(size_t)(tid + 512) * nchpad] = (unsigned short)hist[tid + 511];
    if (tid == 0) ocol[(size_t)1024 * nchpad] = (unsigned short)hist[1023];
}

// K2 (mode): one block per (batch, 4-bucket group). Boundary rows g0..g0+4
// of offsT are loaded coalesced into LDS; per-chunk staging positions come
// from a deterministic in-LDS prefix sum (no atomics, no leader/shfl chain,
// zero global metadata reads in the gather loop). Slices are ~128 B
// contiguous -> ~4x better line utilization than round-2's 32 B reads.
// Phase B: proven batched-CAS hash per sub-bucket with table re-clears.
// XCD swizzle keeps each batch's key stream on one XCD's L2.
// Assumes nchunk <= 256 (N <= 2.09M with CHUNK_S=8192).
__global__ void __launch_bounds__(512)
mode_kernel(const unsigned* __restrict__ keysout,
            const unsigned short* __restrict__ offsT,
            long long N, int nchunk, int nchpad, int bbase,
            unsigned long long* __restrict__ best,   // [NUM_B*NUM_C], zeroed
            double* __restrict__ psum,               // [NUM_B*NGRP]
            unsigned* __restrict__ pcnt)             // [NUM_B*NGRP]
{
    __shared__ unsigned keyt[TAB];                   // 16 KiB, ord or 0
    __shared__ unsigned cnt16[TAB / 2];              // 8 KiB, 2x u16 (count-1)
    __shared__ unsigned staging[4][MODE_CAP];        // 48 KiB, ords per sub
    __shared__ unsigned short rowbuf[5][256];        // 2.5 KiB boundary rows
    __shared__ unsigned short pos[4][256];           // 2 KiB staging prefix
    __shared__ unsigned tot[4];
    __shared__ unsigned long long redb[8];
    __shared__ double reds[8];

    // bijective XCD swizzle (gridDim.x = nbr*256, always % 8 == 0)
    const unsigned nwg = gridDim.x;
    const unsigned logical = (blockIdx.x & 7u) * (nwg >> 3) + (blockIdx.x >> 3);
    const unsigned lb = logical >> 8;
    const unsigned G  = logical & 255u;              // group id
    const unsigned g0 = G << 2;                      // first bucket
    const unsigned c  = G >> 4;                      // class
    const unsigned b  = (unsigned)bbase + lb;
    const int tid = threadIdx.x;
    const int lane = tid & 63, wid = tid >> 6;

    const uint4 z4 = make_uint4(0u, 0u, 0u, 0u);
    for (int i = tid; i < TAB / 4; i += 512) ((uint4*)keyt)[i] = z4;
    for (int i = tid; i < TAB / 8; i += 512) ((uint4*)cnt16)[i] = z4;

    // ---- phase A0: load 5 boundary rows (coalesced) ----
    const unsigned short* obT = offsT + (size_t)lb * 1025 * nchpad;
    for (int i = tid; i < 5 * 256; i += 512) {
        int r = i >> 8, q = i & 255;
        rowbuf[r][q] = (q < nchunk)
            ? obT[(size_t)(g0 + r) * nchpad + q] : (unsigned short)0;
    }
    __syncthreads();

    // ---- phase A1: per-sub-bucket prefix over chunks (4 waves) ----
    if (wid < 4) {
        const int sb = wid;
        unsigned lpre[4], run = 0;
        #pragma unroll
        for (int k = 0; k < 4; ++k) {
            int q = lane * 4 + k;
            lpre[k] = run;
            run += (unsigned)rowbuf[sb + 1][q] - (unsigned)rowbuf[sb][q];
        }
        unsigned inc = run;
        #pragma unroll
        for (int d = 1; d < 64; d <<= 1) {
            unsigned tt = __shfl_up(inc, d);
            if (lane >= d) inc += tt;
        }
        unsigned basex = inc - run;                  // exclusive
        #pragma unroll
        for (int k = 0; k < 4; ++k)
            pos[sb][lane * 4 + k] = (unsigned short)(basex + lpre[k]);
        if (lane == 63) tot[sb] = inc;               // true total
    }
    __syncthreads();

    const unsigned* kb = keysout + (size_t)lb * N;
    double ls = 0.0;
    unsigned mo = 0xFFFFFFFFu;                       // running min ord

    // ---- phase A2: gather slices (16 lanes/chunk, 32 chunks in flight) ----
    const int sub = lane >> 4, j = lane & 15;
    const int nit = (nchunk + 31) >> 5;
    for (int it = 0; it < nit; ++it) {
        int q = it * 32 + wid * 4 + sub;
        if (q < nchunk) {
            unsigned s0 = rowbuf[0][q];
            unsigned rb1 = (unsigned)rowbuf[1][q] - s0;
            unsigned rb2 = (unsigned)rowbuf[2][q] - s0;
            unsigned rb3 = (unsigned)rowbuf[3][q] - s0;
            unsigned len = (unsigned)rowbuf[4][q] - s0;
            const unsigned* src = kb + (size_t)q * CHUNK_S + s0;
            for (unsigned jj = (unsigned)j; jj < len; jj += 16u) {
                unsigned key = src[jj];
                ls += (double)__uint_as_float(key);
                unsigned o = (key & 0x80000000u) ? ~key : (key | 0x80000000u);
                if (o < mo) mo = o;
                int sb = (jj >= rb2) ? ((jj >= rb3) ? 3 : 2)
                                     : ((jj >= rb1) ? 1 : 0);
                unsigned rel = jj - (sb == 0 ? 0u : (sb == 1 ? rb1
                                    : (sb == 2 ? rb2 : rb3)));
                unsigned dst = (unsigned)pos[sb][q] + rel;
                if (dst < MODE_CAP) staging[sb][dst] = o;  // cap: 25 sigma
            }
        }
    }
    __syncthreads();

    // ---- phase B: batched-CAS duplicate counting, per sub-bucket ----
    unsigned bc = 0u, bo = 0xFFFFFFFFu;              // best duplicate
    for (int sb = 0; sb < 4; ++sb) {
        unsigned n = tot[sb]; if (n > MODE_CAP) n = MODE_CAP;
        const unsigned* stg = staging[sb];
        for (unsigned base0 = 0; base0 < n; base0 += 2048u) {
            unsigned od[4], h[4], old[4];
            int nv = 0;
            #pragma unroll
            for (int k = 0; k < 4; ++k) {
                unsigned idx = base0 + (unsigned)tid + (unsigned)k * 512u;
                if (idx < n) {
                    unsigned o = stg[idx];
                    od[k] = o; h[k] = hash_u32(o) & (TAB - 1);
                    nv = k + 1;
                }
            }
            #pragma unroll
            for (int k = 0; k < 4; ++k)              // overlapped first CAS
                if (k < nv) old[k] = atomicCAS(&keyt[h[k]], 0u, od[k]);
            #pragma unroll
            for (int k = 0; k < 4; ++k) {
                if (k >= nv) continue;
                unsigned o = old[k], hh = h[k];
                const unsigned oo = od[k];
                unsigned cnt = 1u;                   // fresh-claim count
                while (o != 0u) {
                    if (o == oo) {                   // duplicate: bump count
                        unsigned sh = (hh & 1u) << 4;
                        unsigned ret = atomicAdd(&cnt16[hh >> 1], 1u << sh);
                        cnt = ((ret >> sh) & 0xFFFFu) + 2u;
                        break;
                    }
                    hh = (hh + 1u) & (TAB - 1u);
                    o = atomicCAS(&keyt[hh], 0u, oo);
                }
                if (cnt >= 2u && (cnt > bc || (cnt == bc && oo < bo))) {
                    bc = cnt; bo = oo;
                }
            }
        }
        if (sb < 3) {                                // re-clear for next sub
            __syncthreads();
            for (int i = tid; i < TAB / 4; i += 512) ((uint4*)keyt)[i] = z4;
            for (int i = tid; i < TAB / 8; i += 512) ((uint4*)cnt16)[i] = z4;
            __syncthreads();
        }
    }

    // epilogue: duplicates carry counts >=2; singletons -> (1, min ord)
    unsigned long long lbst = bc ? (((unsigned long long)bc << 32)
                                    | (unsigned long long)(~bo)) : 0ull;
    {
        unsigned long long s1 = (1ull << 32) | (unsigned long long)(~mo);
        if (s1 > lbst) lbst = s1;
    }
    #pragma unroll
    for (int sh = 32; sh > 0; sh >>= 1) {
        unsigned long long obv = __shfl_down(lbst, sh);
        if (obv > lbst) lbst = obv;
        ls += __shfl_down(ls, sh);
    }
    if (lane == 0) { redb[wid] = lbst; reds[wid] = ls; }
    __syncthreads();
    if (tid == 0) {
        unsigned long long bb = 0ull; double ss = 0.0;
        #pragma unroll
        for (int i = 0; i < 8; ++i) {
            if (redb[i] > bb) bb = redb[i];
            ss += reds[i];
        }
        psum[b * NGRP + G] = ss;
        pcnt[b * NGRP + G] = tot[0] + tot[1] + tot[2] + tot[3];
        if (bb) atomicMax(&best[b * NUM_C + c], bb);
    }
}

// 128 threads, one per (b,c): fold 16 groups, decode mode,
// out = sum_{b,c}(sum - cnt*mode) / (B*N).
__global__ void __launch_bounds__(128)
finalize_kernel(const double* __restrict__ psum,
                const unsigned* __restrict__ pcnt,
                const unsigned long long* __restrict__ best,
                float* __restrict__ out, double inv_total)
{
    __shared__ double acc[NUM_B * NUM_C];
    const int i = threadIdx.x;
    const int b = i >> 4, c = i & 15;

    double s = 0.0;
    unsigned long long cnt = 0ull;
    const double*   ps = psum + (size_t)b * NGRP + ((size_t)c << 4);
    const unsigned* pc = pcnt + (size_t)b * NGRP + ((size_t)c << 4);
    for (int r = 0; r < 16; ++r) { s += ps[r]; cnt += pc[r]; }

    double term = 0.0;
    if (cnt > 0ull) {
        unsigned long long p = best[i];
        unsigned ord = 0xFFFFFFFFu - (unsigned)(p & 0xFFFFFFFFull);
        unsigned ub  = (ord & 0x80000000u) ? (ord ^ 0x80000000u) : ~ord;
        float mode = __uint_as_float(ub);
        term = s - (double)cnt * (double)mode;
    }
    acc[i] = term;
    __syncthreads();
    for (int st = 64; st > 0; st >>= 1) {
        if (i < st) acc[i] += acc[i + st];
        __syncthreads();
    }
    if (i == 0) out[0] = (float)(acc[0] * inv_total);
}

extern "C" void kernel_launch(void* const* d_in, const int* in_sizes, int n_in,
                              void* d_out, int out_size, void* d_ws, size_t ws_size,
                              hipStream_t stream)
{
    const float* x = (const float*)d_in[0];
    const int*   t = (const int*)d_in[1];

    const long long total = in_sizes[0];
    const long long N = total / NUM_B;
    const int nchunk = (int)((N + CHUNK_S - 1) / CHUNK_S);   // 245 for N=2M
    const int nchpad = (nchunk + 63) & ~63;                  // 256

    char* ws = (char*)d_ws;
    size_t off = 0;
    unsigned long long* best = (unsigned long long*)(ws + off);
    off += (size_t)NUM_B * NUM_C * 8;
    double* psum = (double*)(ws + off);
    off += (size_t)NUM_B * NGRP * 8;
    unsigned* pcnt = (unsigned*)(ws + off);
    off += (size_t)NUM_B * NGRP * 4;
    off = (off + 255) & ~(size_t)255;

    const size_t keys_per_b = (size_t)N * 4;
    const size_t offs_per_b = (size_t)1025 * nchpad * 2;
    const size_t per_b = keys_per_b + offs_per_b + 512;
    size_t remaining = ws_size - off;
    int nb = (int)(remaining / per_b);
    if (nb < 1) nb = 1;
    if (nb > MAX_NB) nb = MAX_NB;
    {   // balance rounds (7 -> 4+4, not 7+1)
        int rounds = (NUM_B + nb - 1) / nb;
        nb = (NUM_B + rounds - 1) / rounds;
    }

    unsigned* keysout = (unsigned*)(ws + off);
    off += (size_t)nb * keys_per_b;
    off = (off + 255) & ~(size_t)255;
    unsigned short* offsT = (unsigned short*)(ws + off);
    off += (size_t)nb * offs_per_b;

    hipMemsetAsync(best, 0, (size_t)NUM_B * NUM_C * 8, stream);
    for (int r = 0; r < NUM_B; r += nb) {
        const int nbr = (NUM_B - r < nb) ? (NUM_B - r) : nb;
        sort_kernel<<<nbr * nchunk, 512, 0, stream>>>(
            x, t, N, r, nchunk, nchpad, keysout, offsT);
        mode_kernel<<<nbr * NGRP, 512, 0, stream>>>(
            keysout, offsT, N, nchunk, nchpad, r, best, psum, pcnt);
    }
    finalize_kernel<<<1, 128, 0, stream>>>(
        psum, pcnt, best, (float*)d_out,
        1.0 / ((double)NUM_B * (double)N));
}

// Round 4
// 276.582 us; speedup vs baseline: 1.0832x; 1.0832x over previous
//
#include <hip/hip_runtime.h>
#include <stdint.h>

#define NUM_C 16
#define NUM_B 8
#define NBKT (NUM_C * 64)                // 1024 buckets per batch
#define NGRP 256                         // mode groups (4 buckets each)
#define CHUNK_S 4096                     // items per sort chunk
#define TAB 4096                         // LDS hash slots per mode block
#define MAX_NB 8

__device__ __forceinline__ unsigned hash_u32(unsigned h) {
    h ^= h >> 16; h *= 0x85ebca6bu;
    h ^= h >> 13; h *= 0xc2b2ae35u;
    h ^= h >> 16;
    return h;                            // invertible (xorshift-mul) mixer
}
__device__ __forceinline__ unsigned canon_key(float v) {
    unsigned k = __float_as_uint(v);
    return (k == 0x80000000u) ? 0u : k;  // -0.0 == +0.0
}
__device__ __forceinline__ unsigned bucket_of(unsigned key, int c) {
    return ((unsigned)c << 6) | (hash_u32(key) >> 26);
}

// K1 (fused hist + chunk-local counting sort), 4096-item chunks, 8
// items/thread: keys[8]+pk[8] keeps VGPR ~60 and LDS 20.5 KiB so ~24-32
// waves/CU are resident (round-3 version held 16 items/thread -> ~100 VGPR
// + 36 KiB -> ~16 waves; it was latency-bound at ~9x its HBM floor).
// Offsets written COALESCED per chunk; a separate cheap kernel transposes
// them (round-3 wrote them strided from here: 64B line per 2B store).
__global__ void __launch_bounds__(512)
sort_kernel(const float* __restrict__ x, const int* __restrict__ t,
            long long N, int bbase, int nchunk,
            unsigned* __restrict__ keysout, unsigned short* __restrict__ offs)
{
    __shared__ unsigned hist[NBKT];      // counts -> inclusive scan
    __shared__ unsigned lout[CHUNK_S];   // 16 KiB
    __shared__ unsigned wsum[8];
    const int lb = blockIdx.x / nchunk;
    const int ch = blockIdx.x % nchunk;
    const int b  = bbase + lb;
    const long long base = (long long)ch * CHUNK_S;
    const int count = (int)((N - base < CHUNK_S) ? (N - base) : CHUNK_S);
    const float* xb = x + (size_t)b * N + base;
    const int*   tb = t + (size_t)b * N + base;
    const int tid = threadIdx.x;

    for (int i = tid; i < NBKT; i += 512) hist[i] = 0u;
    __syncthreads();

    unsigned keys[8], pk[8];             // pk = bucket<<13 | rank
    const int n4 = count >> 2;
    #pragma unroll
    for (int r = 0; r < 2; ++r) {
        const int idx4 = tid + r * 512;
        if (idx4 < n4) {
            float4 v  = ((const float4*)xb)[idx4];
            int4   cc = ((const int4*)tb)[idx4];
            unsigned k0 = canon_key(v.x), b0 = bucket_of(k0, cc.x);
            unsigned k1 = canon_key(v.y), b1 = bucket_of(k1, cc.y);
            unsigned k2 = canon_key(v.z), b2 = bucket_of(k2, cc.z);
            unsigned k3 = canon_key(v.w), b3 = bucket_of(k3, cc.w);
            unsigned p0 = atomicAdd(&hist[b0], 1u);
            unsigned p1 = atomicAdd(&hist[b1], 1u);
            unsigned p2 = atomicAdd(&hist[b2], 1u);
            unsigned p3 = atomicAdd(&hist[b3], 1u);
            keys[r*4+0] = k0; pk[r*4+0] = (b0 << 13) | p0;
            keys[r*4+1] = k1; pk[r*4+1] = (b1 << 13) | p1;
            keys[r*4+2] = k2; pk[r*4+2] = (b2 << 13) | p2;
            keys[r*4+3] = k3; pk[r*4+3] = (b3 << 13) | p3;
        }
    }
    unsigned kex = 0u, pkx = 0u; int hex = 0;
    {
        const int remi = (n4 << 2) + tid;  // <=3 tail items
        if (remi < count) {
            unsigned k = canon_key(xb[remi]);
            unsigned bk = bucket_of(k, tb[remi]);
            unsigned p = atomicAdd(&hist[bk], 1u);
            kex = k; pkx = (bk << 13) | p; hex = 1;
        }
    }
    __syncthreads();

    // inclusive scan of hist[0..1023]: 2 bins/thread, wave shfl scan
    {
        unsigned b0v = hist[2 * tid], b1v = hist[2 * tid + 1];
        unsigned s = b0v + b1v, inc = s;
        const int lane = tid & 63;
        #pragma unroll
        for (int d = 1; d < 64; d <<= 1) {
            unsigned tt = __shfl_up(inc, d);
            if (lane >= d) inc += tt;
        }
        if (lane == 63) wsum[tid >> 6] = inc;
        __syncthreads();
        unsigned wbase = 0;
        for (int i = 0; i < (tid >> 6); ++i) wbase += wsum[i];
        unsigned excl = wbase + inc - s;
        hist[2 * tid]     = excl + b0v;
        hist[2 * tid + 1] = excl + s;
        __syncthreads();
    }

    #pragma unroll
    for (int r = 0; r < 2; ++r) {
        const int idx4 = tid + r * 512;
        if (idx4 < n4) {
            #pragma unroll
            for (int c2 = 0; c2 < 4; ++c2) {
                unsigned bk = pk[r*4+c2] >> 13, p = pk[r*4+c2] & 8191u;
                lout[(bk ? hist[bk - 1] : 0u) + p] = keys[r*4+c2];
            }
        }
    }
    if (hex) {
        unsigned bk = pkx >> 13, p = pkx & 8191u;
        lout[(bk ? hist[bk - 1] : 0u) + p] = kex;
    }
    __syncthreads();

    unsigned* kb = keysout + (size_t)lb * N + base;
    if (count == CHUNK_S) {
        #pragma unroll
        for (int r = 0; r < 2; ++r)
            ((uint4*)kb)[tid + r * 512] = ((const uint4*)lout)[tid + r * 512];
    } else {
        for (int i = tid; i < count; i += 512) kb[i] = lout[i];
    }
    // coalesced offsets row: bucket starts [0..1023] + total [1024]
    unsigned short* orow = offs + ((size_t)lb * nchunk + ch) * 1025;
    orow[tid]       = (unsigned short)(tid ? hist[tid - 1] : 0u);
    orow[tid + 512] = (unsigned short)hist[tid + 511];
    if (tid == 0) orow[1024] = (unsigned short)hist[1023];
}

// K1b: tile-transpose offs[ch][row] -> offsT[row][ch] (u16, 32x32 tiles).
// ~16 MB total traffic, both sides coalesced.
__global__ void __launch_bounds__(256)
transpose_kernel(const unsigned short* __restrict__ offs,
                 unsigned short* __restrict__ offsT, int nchunk, int nchpad)
{
    __shared__ unsigned short tile[32][33];
    const int tiles_r = 33;                     // ceil(1025/32)
    const int tiles_c = (nchunk + 31) >> 5;
    const int lb  = blockIdx.x / (tiles_r * tiles_c);
    const int rem = blockIdx.x % (tiles_r * tiles_c);
    const int r0 = (rem / tiles_c) * 32;
    const int c0 = (rem % tiles_c) * 32;
    const unsigned short* src = offs + (size_t)lb * nchunk * 1025;
    unsigned short* dst = offsT + (size_t)lb * 1025 * nchpad;
    const int tx = threadIdx.x & 31, ty = threadIdx.x >> 5;

    #pragma unroll
    for (int dy = 0; dy < 32; dy += 8) {
        int ch = c0 + ty + dy, row = r0 + tx;
        tile[ty + dy][tx] = (ch < nchunk && row < 1025)
            ? src[(size_t)ch * 1025 + row] : (unsigned short)0;
    }
    __syncthreads();
    #pragma unroll
    for (int dy = 0; dy < 32; dy += 8) {
        int row = r0 + ty + dy, ch = c0 + tx;
        if (row < 1025 && ch < nchpad)
            dst[(size_t)row * nchpad + ch] = tile[tx][ty + dy];
    }
}

// K2 (mode): one block per (batch, 4-bucket group), NO staging: per
// sub-bucket session, 4 lanes/chunk stream the (L2-resident) slice and CAS
// directly into the hash table. LDS = 16+8+5 KiB -> full 32-wave occupancy
// (round-3's 78.8 KiB staging version ran at 38% and was latency-bound:
// dur scaled exactly 1/occupancy vs round-0). Table cleared between the 4
// sessions. Singletons need no count (count==1 mode == min value).
__global__ void __launch_bounds__(512)
mode_kernel(const unsigned* __restrict__ keysout,
            const unsigned short* __restrict__ offsT,
            long long N, int nchunk, int nchpad, int bbase,
            unsigned long long* __restrict__ best,   // [NUM_B*NUM_C], zeroed
            double* __restrict__ psum,               // [NUM_B*NGRP]
            unsigned* __restrict__ pcnt)             // [NUM_B*NGRP]
{
    __shared__ unsigned keyt[TAB];                   // 16 KiB, ord or 0
    __shared__ unsigned cnt16[TAB / 2];              // 8 KiB, 2x u16 (count-1)
    __shared__ unsigned short rowbuf[5][512];        // 5 KiB boundary rows
    __shared__ unsigned long long redb[8];
    __shared__ double reds[8];
    __shared__ unsigned redc[8];

    // bijective XCD swizzle (gridDim.x = nbr*256, always % 8 == 0)
    const unsigned nwg = gridDim.x;
    const unsigned logical = (blockIdx.x & 7u) * (nwg >> 3) + (blockIdx.x >> 3);
    const unsigned lb = logical >> 8;
    const unsigned G  = logical & 255u;              // group id
    const unsigned g0 = G << 2;                      // first bucket
    const unsigned c  = G >> 4;                      // class
    const unsigned b  = (unsigned)bbase + lb;
    const int tid = threadIdx.x;
    const int lane = tid & 63, wid = tid >> 6;

    const uint4 z4 = make_uint4(0u, 0u, 0u, 0u);
    for (int i = tid; i < TAB / 4; i += 512) ((uint4*)keyt)[i] = z4;
    for (int i = tid; i < TAB / 8; i += 512) ((uint4*)cnt16)[i] = z4;

    // boundary rows g0..g0+4, coalesced from offsT
    const unsigned short* obT = offsT + (size_t)lb * 1025 * nchpad;
    for (int i = tid; i < 5 * 512; i += 512) {
        int r = i >> 9, q = i & 511;
        rowbuf[r][q] = (q < nchunk)
            ? obT[(size_t)(g0 + r) * nchpad + q] : (unsigned short)0;
    }
    __syncthreads();

    const unsigned* kb = keysout + (size_t)lb * N;
    double ls = 0.0;
    unsigned mo = 0xFFFFFFFFu;                       // running min ord
    unsigned lc = 0u;                                // local item count
    unsigned bc = 0u, bo = 0xFFFFFFFFu;              // best duplicate

    const int nit = (nchunk + 127) >> 7;             // 128 chunks in flight
    for (int sb = 0; sb < 4; ++sb) {
        for (int it = 0; it < nit; ++it) {
            const int q = it * 128 + wid * 16 + (lane >> 2);
            if (q < nchunk) {
                const unsigned s = rowbuf[sb][q];
                const unsigned e = rowbuf[sb + 1][q];
                const unsigned* src = kb + (size_t)q * CHUNK_S;
                for (unsigned jj = s + (unsigned)(lane & 3); jj < e; jj += 4u) {
                    unsigned key = src[jj];
                    ls += (double)__uint_as_float(key);
                    ++lc;
                    unsigned o = (key & 0x80000000u) ? ~key
                                                     : (key | 0x80000000u);
                    if (o < mo) mo = o;
                    unsigned hh = hash_u32(o) & (TAB - 1);
                    unsigned old = atomicCAS(&keyt[hh], 0u, o);
                    unsigned cnt = 1u;               // fresh-claim count
                    while (old != 0u) {
                        if (old == o) {              // duplicate: bump count
                            unsigned sh = (hh & 1u) << 4;
                            unsigned ret =
                                atomicAdd(&cnt16[hh >> 1], 1u << sh);
                            cnt = ((ret >> sh) & 0xFFFFu) + 2u;
                            break;
                        }
                        hh = (hh + 1u) & (TAB - 1u);
                        old = atomicCAS(&keyt[hh], 0u, o);
                    }
                    if (cnt >= 2u && (cnt > bc || (cnt == bc && o < bo))) {
                        bc = cnt; bo = o;
                    }
                }
            }
        }
        if (sb < 3) {                                // re-clear for next sub
            __syncthreads();
            for (int i = tid; i < TAB / 4; i += 512) ((uint4*)keyt)[i] = z4;
            for (int i = tid; i < TAB / 8; i += 512) ((uint4*)cnt16)[i] = z4;
            __syncthreads();
        }
    }

    // epilogue: duplicates carry counts >=2; singletons -> (1, min ord)
    unsigned long long lbst = bc ? (((unsigned long long)bc << 32)
                                    | (unsigned long long)(~bo)) : 0ull;
    {
        unsigned long long s1 = (1ull << 32) | (unsigned long long)(~mo);
        if (s1 > lbst) lbst = s1;
    }
    #pragma unroll
    for (int sh = 32; sh > 0; sh >>= 1) {
        unsigned long long obv = __shfl_down(lbst, sh);
        if (obv > lbst) lbst = obv;
        ls += __shfl_down(ls, sh);
        lc += __shfl_down(lc, sh);
    }
    if (lane == 0) { redb[wid] = lbst; reds[wid] = ls; redc[wid] = lc; }
    __syncthreads();
    if (tid == 0) {
        unsigned long long bb = 0ull; double ss = 0.0; unsigned cc = 0u;
        #pragma unroll
        for (int i = 0; i < 8; ++i) {
            if (redb[i] > bb) bb = redb[i];
            ss += reds[i];
            cc += redc[i];
        }
        psum[b * NGRP + G] = ss;
        pcnt[b * NGRP + G] = cc;
        if (bb) atomicMax(&best[b * NUM_C + c], bb);
    }
}

// 128 threads, one per (b,c): fold 16 groups, decode mode,
// out = sum_{b,c}(sum - cnt*mode) / (B*N).
__global__ void __launch_bounds__(128)
finalize_kernel(const double* __restrict__ psum,
                const unsigned* __restrict__ pcnt,
                const unsigned long long* __restrict__ best,
                float* __restrict__ out, double inv_total)
{
    __shared__ double acc[NUM_B * NUM_C];
    const int i = threadIdx.x;
    const int b = i >> 4, c = i & 15;

    double s = 0.0;
    unsigned long long cnt = 0ull;
    const double*   ps = psum + (size_t)b * NGRP + ((size_t)c << 4);
    const unsigned* pc = pcnt + (size_t)b * NGRP + ((size_t)c << 4);
    for (int r = 0; r < 16; ++r) { s += ps[r]; cnt += pc[r]; }

    double term = 0.0;
    if (cnt > 0ull) {
        unsigned long long p = best[i];
        unsigned ord = 0xFFFFFFFFu - (unsigned)(p & 0xFFFFFFFFull);
        unsigned ub  = (ord & 0x80000000u) ? (ord ^ 0x80000000u) : ~ord;
        float mode = __uint_as_float(ub);
        term = s - (double)cnt * (double)mode;
    }
    acc[i] = term;
    __syncthreads();
    for (int st = 64; st > 0; st >>= 1) {
        if (i < st) acc[i] += acc[i + st];
        __syncthreads();
    }
    if (i == 0) out[0] = (float)(acc[0] * inv_total);
}

extern "C" void kernel_launch(void* const* d_in, const int* in_sizes, int n_in,
                              void* d_out, int out_size, void* d_ws, size_t ws_size,
                              hipStream_t stream)
{
    const float* x = (const float*)d_in[0];
    const int*   t = (const int*)d_in[1];

    const long long total = in_sizes[0];
    const long long N = total / NUM_B;
    const int nchunk = (int)((N + CHUNK_S - 1) / CHUNK_S);   // 489 for N=2M
    const int nchpad = (nchunk + 63) & ~63;                  // 512

    char* ws = (char*)d_ws;
    size_t off = 0;
    unsigned long long* best = (unsigned long long*)(ws + off);
    off += (size_t)NUM_B * NUM_C * 8;
    double* psum = (double*)(ws + off);
    off += (size_t)NUM_B * NGRP * 8;
    unsigned* pcnt = (unsigned*)(ws + off);
    off += (size_t)NUM_B * NGRP * 4;
    off = (off + 255) & ~(size_t)255;

    const size_t keys_per_b  = (size_t)N * 4;
    const size_t offs_per_b  = (size_t)nchunk * 1025 * 2;
    const size_t offsT_per_b = (size_t)1025 * nchpad * 2;
    const size_t per_b = keys_per_b + offs_per_b + offsT_per_b + 512;
    size_t remaining = ws_size - off;
    int nb = (int)(remaining / per_b);
    if (nb < 1) nb = 1;
    if (nb > MAX_NB) nb = MAX_NB;
    {   // balance rounds (7 -> 4+4, not 7+1)
        int rounds = (NUM_B + nb - 1) / nb;
        nb = (NUM_B + rounds - 1) / rounds;
    }

    unsigned* keysout = (unsigned*)(ws + off);
    off += (size_t)nb * keys_per_b;
    off = (off + 255) & ~(size_t)255;
    unsigned short* offsA = (unsigned short*)(ws + off);
    off += (size_t)nb * offs_per_b;
    off = (off + 255) & ~(size_t)255;
    unsigned short* offsT = (unsigned short*)(ws + off);
    off += (size_t)nb * offsT_per_b;

    const int tiles = 33 * ((nchunk + 31) >> 5);
    hipMemsetAsync(best, 0, (size_t)NUM_B * NUM_C * 8, stream);
    for (int r = 0; r < NUM_B; r += nb) {
        const int nbr = (NUM_B - r < nb) ? (NUM_B - r) : nb;
        sort_kernel<<<nbr * nchunk, 512, 0, stream>>>(
            x, t, N, r, nchunk, keysout, offsA);
        transpose_kernel<<<nbr * tiles, 256, 0, stream>>>(
            offsA, offsT, nchunk, nchpad);
        mode_kernel<<<nbr * NGRP, 512, 0, stream>>>(
            keysout, offsT, N, nchunk, nchpad, r, best, psum, pcnt);
    }
    finalize_kernel<<<1, 128, 0, stream>>>(
        psum, pcnt, best, (float*)d_out,
        1.0 / ((double)NUM_B * (double)N));
}